// Round 5
// baseline (328.312 us; speedup 1.0000x reference)
//
#include <hip/hip_runtime.h>

typedef __attribute__((ext_vector_type(8))) short  bf16x8;
typedef __attribute__((ext_vector_type(4))) float  f32x4;

#define S_LEN 4096
#define DH    64
#define NEGF  10000.0f

__device__ __forceinline__ unsigned short f2bf(float f) {
  unsigned u = __float_as_uint(f);
  u += 0x7FFF + ((u >> 16) & 1);          // RNE
  return (unsigned short)(u >> 16);
}

__device__ __forceinline__ bf16x8 pack8(float4 a, float4 b) {
  bf16x8 r;
  r[0] = (short)f2bf(a.x); r[1] = (short)f2bf(a.y);
  r[2] = (short)f2bf(a.z); r[3] = (short)f2bf(a.w);
  r[4] = (short)f2bf(b.x); r[5] = (short)f2bf(b.y);
  r[6] = (short)f2bf(b.z); r[7] = (short)f2bf(b.w);
  return r;
}

// XOR-swizzled byte offset in a [rows][64 bf16] row-major LDS tile (stride 128B)
__device__ __forceinline__ int swz(int row, int colb) {
  return (row << 7) + (colb ^ ((row & 7) << 4));
}

__global__ __launch_bounds__(256, 1)
void attn_fwd(const float* __restrict__ Q, const float* __restrict__ K,
              const float* __restrict__ V, const int* __restrict__ Msk,
              float* __restrict__ O) {
  __shared__ __align__(16) unsigned char smK[8192];   // K  [64 k][64 d] bf16, swizzled
  __shared__ __align__(16) unsigned char smVt[8192];  // V^T[64 d][64 k] bf16, swizzled
  __shared__ __align__(16) unsigned char smP[8192];   // 4 waves x [16 q][64 k] bf16, swizzled

  const int tid  = threadIdx.x;
  const int lane = tid & 63;
  const int wid  = tid >> 6;
  const int p    = lane & 15;   // "column" lane index
  const int h    = lane >> 4;   // quarter index

  const int b  = blockIdx.x >> 6;
  const int qt = blockIdx.x & 63;
  const int q0 = qt << 6;

  const float* Qb = Q + ((size_t)b * S_LEN) * DH;
  const float* Kb = K + ((size_t)b * S_LEN) * DH;
  const float* Vb = V + ((size_t)b * S_LEN) * DH;
  const int*   Mb = Msk + b * S_LEN;

  // ---- Q fragments (A operand: row = lane&15; slots filled with contiguous d) ----
  bf16x8 qf[2];
  {
    const float* qp = Qb + (size_t)(q0 + wid * 16 + p) * DH + h * 8;
    const float4* q4a = (const float4*)(qp);
    const float4* q4b = (const float4*)(qp + 32);
    qf[0] = pack8(q4a[0], q4a[1]);
    qf[1] = pack8(q4b[0], q4b[1]);
  }

  f32x4 o[4];
  float m_r[4], l_r[4];
#pragma unroll
  for (int j = 0; j < 4; ++j) {
#pragma unroll
    for (int e = 0; e < 4; ++e) o[j][e] = 0.f;
  }
#pragma unroll
  for (int r = 0; r < 4; ++r) { m_r[r] = -INFINITY; l_r[r] = 0.f; }

  const int qr_base = q0 + wid * 16 + h * 4;  // + r => this lane's acc rows

  for (int it = 0; it <= qt; ++it) {
    const int kv0 = it << 6;
    __syncthreads();  // prior tile fully consumed before restage

    // ---- stage K (row-major swizzled) and V^T (d-major swizzled) ----
#pragma unroll
    for (int cc = 0; cc < 2; ++cc) {
      // K: thread -> (k-row, 8 d-cols); coalesced float4 x2 loads
      const int chunk = tid + (cc << 8);
      const int row   = chunk >> 3;          // kv row 0..63
      const int colf  = (chunk & 7) << 3;    // d col 0,8,..,56
      const float4* kp = (const float4*)(Kb + (size_t)(kv0 + row) * DH + colf);
      float4 k0 = kp[0], k1 = kp[1];
      *(bf16x8*)(smK + swz(row, colf << 1)) = pack8(k0, k1);

      // V^T: thread -> (d-col, 8 k-rows); per-inst the wave reads 64 consecutive
      // floats of one V row (coalesced); writes one bf16x8 of contiguous k.
      const int dcol = tid & 63;
      const int kc   = (tid >> 6) + (cc << 2);   // 0..7
      bf16x8 vp;
#pragma unroll
      for (int e = 0; e < 8; ++e)
        vp[e] = (short)f2bf(Vb[(size_t)(kv0 + kc * 8 + e) * DH + dcol]);
      *(bf16x8*)(smVt + swz(dcol, kc << 4)) = vp;
    }
    __syncthreads();

    // ---- QK^T : S[q][key], 4 key-subtiles x (K=32 x 2) ----
    f32x4 acc[4];
#pragma unroll
    for (int t = 0; t < 4; ++t) {
      f32x4 a;
#pragma unroll
      for (int e = 0; e < 4; ++e) a[e] = 0.f;
#pragma unroll
      for (int c = 0; c < 2; ++c) {
        bf16x8 kb = *(const bf16x8*)(smK + swz(t * 16 + p, c * 64 + h * 16));
        a = __builtin_amdgcn_mfma_f32_16x16x32_bf16(qf[c], kb, a, 0, 0, 0);
      }
      acc[t] = a;
    }

    // ---- masks + scores ----
    float pen[4];
#pragma unroll
    for (int t = 0; t < 4; ++t)
      pen[t] = Mb[kv0 + t * 16 + p] ? 0.f : -NEGF;

    float sc[4][4];  // [key-subtile][reg-row]
#pragma unroll
    for (int t = 0; t < 4; ++t) {
      const int key = kv0 + t * 16 + p;
#pragma unroll
      for (int r = 0; r < 4; ++r) {
        float v = fmaf(acc[t][r], 0.125f, pen[t]);   // 1/sqrt(64)
        if (key > qr_base + r) v -= NEGF;            // causal (no-op on non-diag tiles)
        sc[t][r] = v;
      }
    }

    // ---- online softmax (row = 4h + r lives in the 16 lanes of quarter h) ----
    float alpha[4];
#pragma unroll
    for (int r = 0; r < 4; ++r) {
      float v = fmaxf(fmaxf(sc[0][r], sc[1][r]), fmaxf(sc[2][r], sc[3][r]));
      v = fmaxf(v, __shfl_xor(v, 1));
      v = fmaxf(v, __shfl_xor(v, 2));
      v = fmaxf(v, __shfl_xor(v, 4));
      v = fmaxf(v, __shfl_xor(v, 8));
      const float mn = fmaxf(m_r[r], v);
      alpha[r] = __expf(m_r[r] - mn);
      m_r[r] = mn;
    }

    unsigned char* Pw = smP + (wid << 11);  // per-wave 2KB region
    float rs[4] = {0.f, 0.f, 0.f, 0.f};
#pragma unroll
    for (int t = 0; t < 4; ++t) {
#pragma unroll
      for (int r = 0; r < 4; ++r) {
        float pv = __expf(sc[t][r] - m_r[r]);
        rs[r] += pv;
        *(unsigned short*)(Pw + swz(h * 4 + r, (t * 16 + p) << 1)) = f2bf(pv);
      }
    }
#pragma unroll
    for (int r = 0; r < 4; ++r) {
      float v = rs[r];
      v += __shfl_xor(v, 1);
      v += __shfl_xor(v, 2);
      v += __shfl_xor(v, 4);
      v += __shfl_xor(v, 8);
      l_r[r] = l_r[r] * alpha[r] + v;
    }
#pragma unroll
    for (int j = 0; j < 4; ++j) {
#pragma unroll
      for (int r = 0; r < 4; ++r) o[j][r] *= alpha[r];
    }

    __syncthreads();  // P visible; keep V^T/K stable until all waves read

    // ---- PV : O[q][d] += P[q][k] * V[k][d] ----
    // A = P (row = lane&15, slots = contiguous k), B = V^T rows (contiguous k):
    // identical slot order on both operands -> internal k-permutation cancels.
    bf16x8 pf[2];
#pragma unroll
    for (int c = 0; c < 2; ++c)
      pf[c] = *(const bf16x8*)(Pw + swz(p, c * 64 + h * 16));

#pragma unroll
    for (int j = 0; j < 4; ++j) {
#pragma unroll
      for (int c = 0; c < 2; ++c) {
        bf16x8 vb = *(const bf16x8*)(smVt + swz(j * 16 + p, c * 64 + h * 16));
        o[j] = __builtin_amdgcn_mfma_f32_16x16x32_bf16(pf[c], vb, o[j], 0, 0, 0);
      }
    }
  }

  // ---- epilogue: O = o / l ----
  float* Ob = O + ((size_t)b * S_LEN) * DH;
#pragma unroll
  for (int r = 0; r < 4; ++r) {
    const float inv = 1.f / l_r[r];
#pragma unroll
    for (int j = 0; j < 4; ++j)
      Ob[(size_t)(qr_base + r) * DH + j * 16 + p] = o[j][r] * inv;
  }
}

// ---------------------------------------------------------------------------
// Degenerate rows: q < f_b where f_b = min{k : mask[b,k]=1}. For those rows
// every visible key carries -10000, matching future unpadded keys, so the
// reference attends over {k <= q} U {k > q, mask=1} with plain softmax(score).
// Recompute those rows in fp32 and overwrite O. Expected ~1-2 rows per batch.
__global__ __launch_bounds__(256, 1)
void fix_degen(const float* __restrict__ Q, const float* __restrict__ K,
               const float* __restrict__ V, const int* __restrict__ Msk,
               float* __restrict__ O) {
  const int b   = blockIdx.x;
  const int tid = threadIdx.x;
  const int lane = tid & 63, w = tid >> 6;

  const float* Qb = Q + (size_t)b * S_LEN * DH;
  const float* Kb = K + (size_t)b * S_LEN * DH;
  const float* Vb = V + (size_t)b * S_LEN * DH;
  const int*   Mb = Msk + b * S_LEN;
  float*       Ob = O + (size_t)b * S_LEN * DH;

  __shared__ int   sf;
  __shared__ float sq[DH];
  __shared__ float ssc[S_LEN];
  __shared__ float sred[8];
  __shared__ float spart[4][DH];

  if (tid == 0) sf = S_LEN;
  __syncthreads();
  int loc = S_LEN;
  for (int k = tid; k < S_LEN; k += 256)
    if (Mb[k]) { loc = k; break; }
  atomicMin(&sf, loc);
  __syncthreads();
  const int fb = sf;

  for (int q = 0; q < fb; ++q) {
    if (tid < DH) sq[tid] = Qb[(size_t)q * DH + tid];
    __syncthreads();

    float lmax = -1e30f;
    for (int k = tid; k < S_LEN; k += 256) {
      float s = -1e30f;
      if (k <= q || Mb[k]) {
        float acc = 0.f;
#pragma unroll
        for (int d = 0; d < DH; ++d) acc = fmaf(sq[d], Kb[(size_t)k * DH + d], acc);
        s = acc * 0.125f;
      }
      ssc[k] = s;
      lmax = fmaxf(lmax, s);
    }
#pragma unroll
    for (int o2 = 32; o2; o2 >>= 1) lmax = fmaxf(lmax, __shfl_xor(lmax, o2));
    if (lane == 0) sred[w] = lmax;
    __syncthreads();
    const float gmax = fmaxf(fmaxf(sred[0], sred[1]), fmaxf(sred[2], sred[3]));

    float lsum = 0.f;
    for (int k = tid; k < S_LEN; k += 256) {
      float e = (ssc[k] > -1e29f) ? __expf(ssc[k] - gmax) : 0.f;
      ssc[k] = e;
      lsum += e;
    }
#pragma unroll
    for (int o2 = 32; o2; o2 >>= 1) lsum += __shfl_xor(lsum, o2);
    if (lane == 0) sred[4 + w] = lsum;
    __syncthreads();
    const float inv = 1.f / (sred[4] + sred[5] + sred[6] + sred[7]);

    const int d = tid & 63, c = tid >> 6;
    float part = 0.f;
    for (int k = c * (S_LEN / 4); k < (c + 1) * (S_LEN / 4); ++k)
      part = fmaf(ssc[k], Vb[(size_t)k * DH + d], part);
    spart[c][d] = part;
    __syncthreads();
    if (tid < DH)
      Ob[(size_t)q * DH + tid] =
          (spart[0][tid] + spart[1][tid] + spart[2][tid] + spart[3][tid]) * inv;
    __syncthreads();
  }
}

extern "C" void kernel_launch(void* const* d_in, const int* in_sizes, int n_in,
                              void* d_out, int out_size, void* d_ws, size_t ws_size,
                              hipStream_t stream) {
  const float* Q = (const float*)d_in[0];
  const float* K = (const float*)d_in[1];
  const float* V = (const float*)d_in[2];
  const int*   M = (const int*)d_in[3];
  float* O = (float*)d_out;
  attn_fwd<<<dim3(4 * (S_LEN / 64)), dim3(256), 0, stream>>>(Q, K, V, M, O);
  fix_degen<<<dim3(4), dim3(256), 0, stream>>>(Q, K, V, M, O);
}

// Round 6
// 251.697 us; speedup vs baseline: 1.3044x; 1.3044x over previous
//
#include <hip/hip_runtime.h>

typedef __attribute__((ext_vector_type(8))) short  bf16x8;
typedef __attribute__((ext_vector_type(4))) float  f32x4;

#define S_LEN 4096
#define DH    64
#define NEGF  10000.0f

__device__ __forceinline__ unsigned short f2bf(float f) {
  unsigned u = __float_as_uint(f);
  u += 0x7FFF + ((u >> 16) & 1);          // RNE
  return (unsigned short)(u >> 16);
}

__device__ __forceinline__ bf16x8 pack8(float4 a, float4 b) {
  bf16x8 r;
  r[0] = (short)f2bf(a.x); r[1] = (short)f2bf(a.y);
  r[2] = (short)f2bf(a.z); r[3] = (short)f2bf(a.w);
  r[4] = (short)f2bf(b.x); r[5] = (short)f2bf(b.y);
  r[6] = (short)f2bf(b.z); r[7] = (short)f2bf(b.w);
  return r;
}

// XOR-swizzled byte offset in a [rows][64 bf16] row-major LDS tile (stride 128B)
__device__ __forceinline__ int swz(int row, int colb) {
  return (row << 7) + (colb ^ ((row & 7) << 4));
}

// 16 waves: q-group g = wid>>2 (16 rows each), KV phase r = wid&3.
// Phase r processes KV tiles j === r (mod 4) with its own online-softmax
// partial; partials merged through LDS at the end.
__global__ __launch_bounds__(1024, 1)
void attn_fwd(const float* __restrict__ Q, const float* __restrict__ K,
              const float* __restrict__ V, const int* __restrict__ Msk,
              float* __restrict__ O) {
  __shared__ __align__(16) unsigned char smem[98304];
  unsigned char* smK  = smem;           // 4 tiles x [64 k][64 d] bf16 swizzled (32KB)
  unsigned char* smVt = smem + 32768;   // 4 tiles x [64 d][64 k] bf16 swizzled (32KB)
  unsigned char* smP  = smem + 65536;   // 16 waves x [16 q][64 k] bf16 swizzled (32KB)

  const int tid  = threadIdx.x;
  const int lane = tid & 63;
  const int wid  = tid >> 6;
  const int g    = wid >> 2;    // q-row group (0..3)
  const int r    = wid & 3;     // KV phase   (0..3)
  const int p    = lane & 15;
  const int h    = lane >> 4;

  const int b  = blockIdx.x >> 6;
  const int qt = blockIdx.x & 63;
  const int q0 = qt << 6;

  const float* Qb = Q + ((size_t)b * S_LEN) * DH;
  const float* Kb = K + ((size_t)b * S_LEN) * DH;
  const float* Vb = V + ((size_t)b * S_LEN) * DH;
  const int*   Mb = Msk + b * S_LEN;

  // ---- Q fragments (A operand: row = lane&15; slots = contiguous d) ----
  bf16x8 qf[2];
  {
    const float* qp = Qb + (size_t)(q0 + g * 16 + p) * DH + h * 8;
    const float4* q4a = (const float4*)(qp);
    const float4* q4b = (const float4*)(qp + 32);
    qf[0] = pack8(q4a[0], q4a[1]);
    qf[1] = pack8(q4b[0], q4b[1]);
  }

  f32x4 o[4];
  float m_r[4], l_r[4];
#pragma unroll
  for (int j = 0; j < 4; ++j)
#pragma unroll
    for (int e = 0; e < 4; ++e) o[j][e] = 0.f;
#pragma unroll
  for (int rr = 0; rr < 4; ++rr) { m_r[rr] = -INFINITY; l_r[rr] = 0.f; }

  const int qrb = q0 + g * 16 + h * 4;  // + rr => this lane's acc rows

  const int ns = (qt >> 2) + 1;         // ceil((qt+1)/4)
  for (int s = 0; s < ns; ++s) {
    const int kb4 = s << 2;             // first KV tile of this super-iter
    __syncthreads();                    // prior iter fully consumed

    // ---- stage 4 K tiles + 4 V^T tiles ----
#pragma unroll
    for (int cc = 0; cc < 2; ++cc) {
      const int idx = tid + (cc << 10);          // 0..2047
      // K: chunk -> (tile, k-row, 8 d-cols)
      {
        const int row256 = idx >> 3;
        const int colf   = (idx & 7) << 3;
        const int t      = row256 >> 6;
        const int row    = row256 & 63;
        if (kb4 + t <= qt) {
          const float4* kp =
              (const float4*)(Kb + (size_t)((kb4 + t) * 64 + row) * DH + colf);
          float4 k0 = kp[0], k1 = kp[1];
          *(bf16x8*)(smK + t * 8192 + swz(row, colf << 1)) = pack8(k0, k1);
        }
      }
      // V^T: chunk -> (tile, d-col, 8 k-rows)
      {
        const int t2   = idx >> 9;
        const int i    = idx & 511;
        const int dcol = i & 63;
        const int kc   = i >> 6;
        if (kb4 + t2 <= qt) {
          bf16x8 vp;
#pragma unroll
          for (int e = 0; e < 8; ++e)
            vp[e] = (short)f2bf(
                Vb[(size_t)((kb4 + t2) * 64 + kc * 8 + e) * DH + dcol]);
          *(bf16x8*)(smVt + t2 * 8192 + swz(dcol, kc << 4)) = vp;
        }
      }
    }
    __syncthreads();

    const int j = kb4 + r;              // this wave's KV tile
    if (j <= qt) {
      const int kv0 = j << 6;
      const unsigned char* myK  = smK  + r * 8192;
      const unsigned char* myVt = smVt + r * 8192;

      // ---- QK^T ----
      f32x4 acc[4];
#pragma unroll
      for (int t16 = 0; t16 < 4; ++t16) {
        f32x4 a;
#pragma unroll
        for (int e = 0; e < 4; ++e) a[e] = 0.f;
#pragma unroll
        for (int c = 0; c < 2; ++c) {
          bf16x8 kb = *(const bf16x8*)(myK + swz(t16 * 16 + p, c * 64 + h * 16));
          a = __builtin_amdgcn_mfma_f32_16x16x32_bf16(qf[c], kb, a, 0, 0, 0);
        }
        acc[t16] = a;
      }

      // ---- masks + scores ----
      float pen[4];
#pragma unroll
      for (int t16 = 0; t16 < 4; ++t16)
        pen[t16] = Mb[kv0 + t16 * 16 + p] ? 0.f : -NEGF;

      float sc[4][4];
#pragma unroll
      for (int t16 = 0; t16 < 4; ++t16) {
        const int key = kv0 + t16 * 16 + p;
#pragma unroll
        for (int rr = 0; rr < 4; ++rr) {
          float v = fmaf(acc[t16][rr], 0.125f, pen[t16]);
          if (key > qrb + rr) v -= NEGF;          // causal
          sc[t16][rr] = v;
        }
      }

      // ---- online softmax (phase-local partial) ----
      float alpha[4];
#pragma unroll
      for (int rr = 0; rr < 4; ++rr) {
        float v = fmaxf(fmaxf(sc[0][rr], sc[1][rr]), fmaxf(sc[2][rr], sc[3][rr]));
        v = fmaxf(v, __shfl_xor(v, 1));
        v = fmaxf(v, __shfl_xor(v, 2));
        v = fmaxf(v, __shfl_xor(v, 4));
        v = fmaxf(v, __shfl_xor(v, 8));
        const float mn = fmaxf(m_r[rr], v);
        alpha[rr] = __expf(m_r[rr] - mn);
        m_r[rr] = mn;
      }

      unsigned char* Pw = smP + (wid << 11);
      float rs[4] = {0.f, 0.f, 0.f, 0.f};
#pragma unroll
      for (int t16 = 0; t16 < 4; ++t16) {
#pragma unroll
        for (int rr = 0; rr < 4; ++rr) {
          float pv = __expf(sc[t16][rr] - m_r[rr]);
          rs[rr] += pv;
          *(unsigned short*)(Pw + swz(h * 4 + rr, (t16 * 16 + p) << 1)) = f2bf(pv);
        }
      }
#pragma unroll
      for (int rr = 0; rr < 4; ++rr) {
        float v = rs[rr];
        v += __shfl_xor(v, 1);
        v += __shfl_xor(v, 2);
        v += __shfl_xor(v, 4);
        v += __shfl_xor(v, 8);
        l_r[rr] = l_r[rr] * alpha[rr] + v;
      }
#pragma unroll
      for (int jj = 0; jj < 4; ++jj)
#pragma unroll
        for (int rr = 0; rr < 4; ++rr) o[jj][rr] *= alpha[rr];

      // same-wave P write -> P read: drain LDS, keep reads below
      asm volatile("s_waitcnt lgkmcnt(0)" ::: "memory");
      __builtin_amdgcn_sched_barrier(0);

      // ---- PV ----
      bf16x8 pf[2];
#pragma unroll
      for (int c = 0; c < 2; ++c)
        pf[c] = *(const bf16x8*)(Pw + swz(p, c * 64 + h * 16));
#pragma unroll
      for (int jj = 0; jj < 4; ++jj)
#pragma unroll
        for (int c = 0; c < 2; ++c) {
          bf16x8 vb = *(const bf16x8*)(myVt + swz(jj * 16 + p, c * 64 + h * 16));
          o[jj] = __builtin_amdgcn_mfma_f32_16x16x32_bf16(pf[c], vb, o[jj], 0, 0, 0);
        }
    }
  }

  // ---- merge the 4 phase-partials per q-group through LDS ----
  __syncthreads();                       // all compute done; smem reusable
  {
    float* wb = (float*)smem + wid * 1536 + lane * 24;
#pragma unroll
    for (int rr = 0; rr < 4; ++rr) { wb[rr] = m_r[rr]; wb[4 + rr] = l_r[rr]; }
#pragma unroll
    for (int jj = 0; jj < 4; ++jj)
#pragma unroll
      for (int rr = 0; rr < 4; ++rr) wb[8 + jj * 4 + rr] = o[jj][rr];
  }
  __syncthreads();

  if (r == 0) {
    const float* b0 = (float*)smem + (wid + 0) * 1536 + lane * 24;
    const float* b1 = (float*)smem + (wid + 1) * 1536 + lane * 24;
    const float* b2 = (float*)smem + (wid + 2) * 1536 + lane * 24;
    const float* b3 = (float*)smem + (wid + 3) * 1536 + lane * 24;
    float* Ob = O + ((size_t)b * S_LEN) * DH;
#pragma unroll
    for (int rr = 0; rr < 4; ++rr) {
      const float M = fmaxf(fmaxf(b0[rr], b1[rr]), fmaxf(b2[rr], b3[rr]));
      const float w0 = __expf(b0[rr] - M), w1 = __expf(b1[rr] - M);
      const float w2 = __expf(b2[rr] - M), w3 = __expf(b3[rr] - M);
      const float L = b0[4 + rr] * w0 + b1[4 + rr] * w1 +
                      b2[4 + rr] * w2 + b3[4 + rr] * w3;
      const float inv = 1.f / L;
#pragma unroll
      for (int jj = 0; jj < 4; ++jj) {
        const float num = b0[8 + jj * 4 + rr] * w0 + b1[8 + jj * 4 + rr] * w1 +
                          b2[8 + jj * 4 + rr] * w2 + b3[8 + jj * 4 + rr] * w3;
        Ob[(size_t)(qrb + rr) * DH + jj * 16 + p] = num * inv;
      }
    }
  }
}

// ---------------------------------------------------------------------------
// Degenerate rows: q < f_b where f_b = min{k : mask[b,k]=1}. For those rows
// every visible key carries -10000, matching future unpadded keys, so the
// reference attends over {k <= q} U {k > q, mask=1} with plain softmax(score).
__global__ __launch_bounds__(256, 1)
void fix_degen(const float* __restrict__ Q, const float* __restrict__ K,
               const float* __restrict__ V, const int* __restrict__ Msk,
               float* __restrict__ O) {
  const int b   = blockIdx.x;
  const int tid = threadIdx.x;
  const int lane = tid & 63, w = tid >> 6;

  const float* Qb = Q + (size_t)b * S_LEN * DH;
  const float* Kb = K + (size_t)b * S_LEN * DH;
  const float* Vb = V + (size_t)b * S_LEN * DH;
  const int*   Mb = Msk + b * S_LEN;
  float*       Ob = O + (size_t)b * S_LEN * DH;

  __shared__ int   sf;
  __shared__ float sq[DH];
  __shared__ float ssc[S_LEN];
  __shared__ float sred[8];
  __shared__ float spart[4][DH];

  if (tid == 0) sf = S_LEN;
  __syncthreads();
  int loc = S_LEN;
  for (int k = tid; k < S_LEN; k += 256)
    if (Mb[k]) { loc = k; break; }
  atomicMin(&sf, loc);
  __syncthreads();
  const int fb = sf;

  for (int q = 0; q < fb; ++q) {
    if (tid < DH) sq[tid] = Qb[(size_t)q * DH + tid];
    __syncthreads();

    float lmax = -1e30f;
    for (int k = tid; k < S_LEN; k += 256) {
      float s = -1e30f;
      if (k <= q || Mb[k]) {
        float acc = 0.f;
#pragma unroll
        for (int d = 0; d < DH; ++d) acc = fmaf(sq[d], Kb[(size_t)k * DH + d], acc);
        s = acc * 0.125f;
      }
      ssc[k] = s;
      lmax = fmaxf(lmax, s);
    }
#pragma unroll
    for (int o2 = 32; o2; o2 >>= 1) lmax = fmaxf(lmax, __shfl_xor(lmax, o2));
    if (lane == 0) sred[w] = lmax;
    __syncthreads();
    const float gmax = fmaxf(fmaxf(sred[0], sred[1]), fmaxf(sred[2], sred[3]));

    float lsum = 0.f;
    for (int k = tid; k < S_LEN; k += 256) {
      float e = (ssc[k] > -1e29f) ? __expf(ssc[k] - gmax) : 0.f;
      ssc[k] = e;
      lsum += e;
    }
#pragma unroll
    for (int o2 = 32; o2; o2 >>= 1) lsum += __shfl_xor(lsum, o2);
    if (lane == 0) sred[4 + w] = lsum;
    __syncthreads();
    const float inv = 1.f / (sred[4] + sred[5] + sred[6] + sred[7]);

    const int d = tid & 63, c = tid >> 6;
    float part = 0.f;
    for (int k = c * (S_LEN / 4); k < (c + 1) * (S_LEN / 4); ++k)
      part = fmaf(ssc[k], Vb[(size_t)k * DH + d], part);
    spart[c][d] = part;
    __syncthreads();
    if (tid < DH)
      Ob[(size_t)q * DH + tid] =
          (spart[0][tid] + spart[1][tid] + spart[2][tid] + spart[3][tid]) * inv;
    __syncthreads();
  }
}

extern "C" void kernel_launch(void* const* d_in, const int* in_sizes, int n_in,
                              void* d_out, int out_size, void* d_ws, size_t ws_size,
                              hipStream_t stream) {
  const float* Q = (const float*)d_in[0];
  const float* K = (const float*)d_in[1];
  const float* V = (const float*)d_in[2];
  const int*   M = (const int*)d_in[3];
  float* O = (float*)d_out;
  attn_fwd<<<dim3(4 * (S_LEN / 64)), dim3(1024), 0, stream>>>(Q, K, V, M, O);
  fix_degen<<<dim3(4), dim3(256), 0, stream>>>(Q, K, V, M, O);
}

// Round 7
// 146.155 us; speedup vs baseline: 2.2463x; 1.7221x over previous
//
#include <hip/hip_runtime.h>

typedef __attribute__((ext_vector_type(8))) short  bf16x8;
typedef __attribute__((ext_vector_type(4))) float  f32x4;

#define S_LEN 4096
#define DH    64
#define NEGF  10000.0f

__device__ __forceinline__ unsigned short f2bf(float f) {
  unsigned u = __float_as_uint(f);
  u += 0x7FFF + ((u >> 16) & 1);          // RNE
  return (unsigned short)(u >> 16);
}

__device__ __forceinline__ bf16x8 pack8(float4 a, float4 b) {
  bf16x8 r;
  r[0] = (short)f2bf(a.x); r[1] = (short)f2bf(a.y);
  r[2] = (short)f2bf(a.z); r[3] = (short)f2bf(a.w);
  r[4] = (short)f2bf(b.x); r[5] = (short)f2bf(b.y);
  r[6] = (short)f2bf(b.z); r[7] = (short)f2bf(b.w);
  return r;
}

// XOR-swizzled byte offset in a [rows][64 bf16] row-major LDS tile (stride 128B)
__device__ __forceinline__ int swz(int row, int colb) {
  return (row << 7) + (colb ^ ((row & 7) << 4));
}

// 16 waves: q-group g = wid>>2 (16 rows each), KV phase r = wid&3.
// Phase r processes KV tiles j === r (mod 4) with its own online-softmax
// partial; partials merged through LDS at the end.
// Degenerate rows (q < fb, fb = first unmasked key) are recomputed with
// reference additive-mask semantics by block (b, qt = q & 64-1) after its
// main work; the merge write skips them so each row has exactly one writer.
__global__ __launch_bounds__(1024, 1)
void attn_fwd(const float* __restrict__ Q, const float* __restrict__ K,
              const float* __restrict__ V, const int* __restrict__ Msk,
              float* __restrict__ O) {
  __shared__ __align__(16) unsigned char smem[98304];
  __shared__ int sfb;
  unsigned char* smK  = smem;           // 4 tiles x [64 k][64 d] bf16 swizzled (32KB)
  unsigned char* smVt = smem + 32768;   // 4 tiles x [64 d][64 k] bf16 swizzled (32KB)
  unsigned char* smP  = smem + 65536;   // 16 waves x [16 q][64 k] bf16 swizzled (32KB)

  const int tid  = threadIdx.x;
  const int lane = tid & 63;
  const int wid  = tid >> 6;
  const int g    = wid >> 2;    // q-row group (0..3)
  const int r    = wid & 3;     // KV phase   (0..3)
  const int p    = lane & 15;
  const int h    = lane >> 4;

  const int b  = blockIdx.x >> 6;
  const int qt = blockIdx.x & 63;
  const int q0 = qt << 6;

  const float* Qb = Q + ((size_t)b * S_LEN) * DH;
  const float* Kb = K + ((size_t)b * S_LEN) * DH;
  const float* Vb = V + ((size_t)b * S_LEN) * DH;
  const int*   Mb = Msk + b * S_LEN;

  // ---- fb = min{k : mask[b,k]=1} (block-uniform) ----
  if (tid == 0) sfb = S_LEN;
  __syncthreads();
  {
    int loc = S_LEN;
    for (int k = tid; k < S_LEN; k += 1024)
      if (Mb[k]) { loc = k; break; }
    if (loc < S_LEN) atomicMin(&sfb, loc);
  }
  __syncthreads();
  const int fb = sfb;

  // ---- Q fragments (A operand: row = lane&15; slots = contiguous d) ----
  bf16x8 qf[2];
  {
    const float* qp = Qb + (size_t)(q0 + g * 16 + p) * DH + h * 8;
    const float4* q4a = (const float4*)(qp);
    const float4* q4b = (const float4*)(qp + 32);
    qf[0] = pack8(q4a[0], q4a[1]);
    qf[1] = pack8(q4b[0], q4b[1]);
  }

  f32x4 o[4];
  float m_r[4], l_r[4];
#pragma unroll
  for (int j = 0; j < 4; ++j)
#pragma unroll
    for (int e = 0; e < 4; ++e) o[j][e] = 0.f;
#pragma unroll
  for (int rr = 0; rr < 4; ++rr) { m_r[rr] = -INFINITY; l_r[rr] = 0.f; }

  const int qrb = q0 + g * 16 + h * 4;  // + rr => this lane's acc rows

  const int ns = (qt >> 2) + 1;         // ceil((qt+1)/4)
  for (int s = 0; s < ns; ++s) {
    const int kb4 = s << 2;             // first KV tile of this super-iter
    __syncthreads();                    // prior iter fully consumed

    // ---- stage 4 K tiles + 4 V^T tiles ----
#pragma unroll
    for (int cc = 0; cc < 2; ++cc) {
      const int idx = tid + (cc << 10);          // 0..2047
      // K: chunk -> (tile, k-row, 8 d-cols)
      {
        const int row256 = idx >> 3;
        const int colf   = (idx & 7) << 3;
        const int t      = row256 >> 6;
        const int row    = row256 & 63;
        if (kb4 + t <= qt) {
          const float4* kp =
              (const float4*)(Kb + (size_t)((kb4 + t) * 64 + row) * DH + colf);
          float4 k0 = kp[0], k1 = kp[1];
          *(bf16x8*)(smK + t * 8192 + swz(row, colf << 1)) = pack8(k0, k1);
        }
      }
      // V^T: chunk -> (tile, d-col, 8 k-rows)
      {
        const int t2   = idx >> 9;
        const int i    = idx & 511;
        const int dcol = i & 63;
        const int kc   = i >> 6;
        if (kb4 + t2 <= qt) {
          bf16x8 vp;
#pragma unroll
          for (int e = 0; e < 8; ++e)
            vp[e] = (short)f2bf(
                Vb[(size_t)((kb4 + t2) * 64 + kc * 8 + e) * DH + dcol]);
          *(bf16x8*)(smVt + t2 * 8192 + swz(dcol, kc << 4)) = vp;
        }
      }
    }
    __syncthreads();

    const int j = kb4 + r;              // this wave's KV tile
    if (j <= qt) {
      const int kv0 = j << 6;
      const unsigned char* myK  = smK  + r * 8192;
      const unsigned char* myVt = smVt + r * 8192;

      // ---- QK^T ----
      f32x4 acc[4];
#pragma unroll
      for (int t16 = 0; t16 < 4; ++t16) {
        f32x4 a;
#pragma unroll
        for (int e = 0; e < 4; ++e) a[e] = 0.f;
#pragma unroll
        for (int c = 0; c < 2; ++c) {
          bf16x8 kb = *(const bf16x8*)(myK + swz(t16 * 16 + p, c * 64 + h * 16));
          a = __builtin_amdgcn_mfma_f32_16x16x32_bf16(qf[c], kb, a, 0, 0, 0);
        }
        acc[t16] = a;
      }

      // ---- masks + scores ----
      float pen[4];
#pragma unroll
      for (int t16 = 0; t16 < 4; ++t16)
        pen[t16] = Mb[kv0 + t16 * 16 + p] ? 0.f : -NEGF;

      float sc[4][4];
#pragma unroll
      for (int t16 = 0; t16 < 4; ++t16) {
        const int key = kv0 + t16 * 16 + p;
#pragma unroll
        for (int rr = 0; rr < 4; ++rr) {
          float v = fmaf(acc[t16][rr], 0.125f, pen[t16]);
          if (key > qrb + rr) v -= NEGF;          // causal
          sc[t16][rr] = v;
        }
      }

      // ---- online softmax (phase-local partial) ----
      float alpha[4];
#pragma unroll
      for (int rr = 0; rr < 4; ++rr) {
        float v = fmaxf(fmaxf(sc[0][rr], sc[1][rr]), fmaxf(sc[2][rr], sc[3][rr]));
        v = fmaxf(v, __shfl_xor(v, 1));
        v = fmaxf(v, __shfl_xor(v, 2));
        v = fmaxf(v, __shfl_xor(v, 4));
        v = fmaxf(v, __shfl_xor(v, 8));
        const float mn = fmaxf(m_r[rr], v);
        alpha[rr] = __expf(m_r[rr] - mn);
        m_r[rr] = mn;
      }

      unsigned char* Pw = smP + (wid << 11);
      float rs[4] = {0.f, 0.f, 0.f, 0.f};
#pragma unroll
      for (int t16 = 0; t16 < 4; ++t16) {
#pragma unroll
        for (int rr = 0; rr < 4; ++rr) {
          float pv = __expf(sc[t16][rr] - m_r[rr]);
          rs[rr] += pv;
          *(unsigned short*)(Pw + swz(h * 4 + rr, (t16 * 16 + p) << 1)) = f2bf(pv);
        }
      }
#pragma unroll
      for (int rr = 0; rr < 4; ++rr) {
        float v = rs[rr];
        v += __shfl_xor(v, 1);
        v += __shfl_xor(v, 2);
        v += __shfl_xor(v, 4);
        v += __shfl_xor(v, 8);
        l_r[rr] = l_r[rr] * alpha[rr] + v;
      }
#pragma unroll
      for (int jj = 0; jj < 4; ++jj)
#pragma unroll
        for (int rr = 0; rr < 4; ++rr) o[jj][rr] *= alpha[rr];

      // same-wave P write -> P read: drain LDS, keep reads below
      asm volatile("s_waitcnt lgkmcnt(0)" ::: "memory");
      __builtin_amdgcn_sched_barrier(0);

      // ---- PV ----
      bf16x8 pf[2];
#pragma unroll
      for (int c = 0; c < 2; ++c)
        pf[c] = *(const bf16x8*)(Pw + swz(p, c * 64 + h * 16));
#pragma unroll
      for (int jj = 0; jj < 4; ++jj)
#pragma unroll
        for (int c = 0; c < 2; ++c) {
          bf16x8 vb = *(const bf16x8*)(myVt + swz(jj * 16 + p, c * 64 + h * 16));
          o[jj] = __builtin_amdgcn_mfma_f32_16x16x32_bf16(pf[c], vb, o[jj], 0, 0, 0);
        }
    }
  }

  // ---- merge the 4 phase-partials per q-group through LDS ----
  __syncthreads();                       // all compute done; smem reusable
  {
    float* wb = (float*)smem + wid * 1536 + lane * 24;
#pragma unroll
    for (int rr = 0; rr < 4; ++rr) { wb[rr] = m_r[rr]; wb[4 + rr] = l_r[rr]; }
#pragma unroll
    for (int jj = 0; jj < 4; ++jj)
#pragma unroll
      for (int rr = 0; rr < 4; ++rr) wb[8 + jj * 4 + rr] = o[jj][rr];
  }
  __syncthreads();

  if (r == 0) {
    const float* b0 = (float*)smem + (wid + 0) * 1536 + lane * 24;
    const float* b1 = (float*)smem + (wid + 1) * 1536 + lane * 24;
    const float* b2 = (float*)smem + (wid + 2) * 1536 + lane * 24;
    const float* b3 = (float*)smem + (wid + 3) * 1536 + lane * 24;
    float* Ob = O + ((size_t)b * S_LEN) * DH;
#pragma unroll
    for (int rr = 0; rr < 4; ++rr) {
      if (qrb + rr < fb) continue;       // degen row: written by its degen owner
      const float M = fmaxf(fmaxf(b0[rr], b1[rr]), fmaxf(b2[rr], b3[rr]));
      const float w0 = __expf(b0[rr] - M), w1 = __expf(b1[rr] - M);
      const float w2 = __expf(b2[rr] - M), w3 = __expf(b3[rr] - M);
      const float L = b0[4 + rr] * w0 + b1[4 + rr] * w1 +
                      b2[4 + rr] * w2 + b3[4 + rr] * w3;
      const float inv = 1.f / L;
#pragma unroll
      for (int jj = 0; jj < 4; ++jj) {
        const float num = b0[8 + jj * 4 + rr] * w0 + b1[8 + jj * 4 + rr] * w1 +
                          b2[8 + jj * 4 + rr] * w2 + b3[8 + jj * 4 + rr] * w3;
        Ob[(size_t)(qrb + rr) * DH + jj * 16 + p] = num * inv;
      }
    }
  }

  // ---- degenerate rows: q ≡ qt (mod 64), q < fb ----
  // Reference semantics: all visible keys carry -10000, tying with future
  // unmasked keys -> softmax over {k <= q} U {mask=1} on raw scores.
  for (int dq = qt; dq < fb; dq += 64) {
    __syncthreads();                     // merge reads done; smem reusable
    float* ssc   = (float*)smem;         // [4096] exp-scores
    float* sq    = (float*)smem + 4096;  // [64] q-vector
    float* spart = (float*)smem + 4160;  // [16][64] wave PV partials
    float* sred  = (float*)smem + 5184;  // [32] reduction scratch
    if (tid < 64) sq[tid] = Qb[(size_t)dq * DH + tid];
    __syncthreads();

    float lmax = -1e30f;
    for (int k = tid; k < S_LEN; k += 1024) {
      float s = -1e30f;
      if (k <= dq || Mb[k]) {
        const float4* kp = (const float4*)(Kb + (size_t)k * DH);
        float acc = 0.f;
#pragma unroll
        for (int d4 = 0; d4 < 16; ++d4) {
          const float4 kv = kp[d4];
          acc += sq[d4 * 4 + 0] * kv.x + sq[d4 * 4 + 1] * kv.y +
                 sq[d4 * 4 + 2] * kv.z + sq[d4 * 4 + 3] * kv.w;
        }
        s = acc * 0.125f;
      }
      ssc[k] = s;
      lmax = fmaxf(lmax, s);
    }
#pragma unroll
    for (int o2 = 32; o2; o2 >>= 1) lmax = fmaxf(lmax, __shfl_xor(lmax, o2));
    if (lane == 0) sred[wid] = lmax;
    __syncthreads();
    float gmax = sred[0];
#pragma unroll
    for (int i = 1; i < 16; ++i) gmax = fmaxf(gmax, sred[i]);

    float lsum = 0.f;
    for (int k = tid; k < S_LEN; k += 1024) {
      const float e = (ssc[k] > -1e29f) ? __expf(ssc[k] - gmax) : 0.f;
      ssc[k] = e;
      lsum += e;
    }
#pragma unroll
    for (int o2 = 32; o2; o2 >>= 1) lsum += __shfl_xor(lsum, o2);
    if (lane == 0) sred[16 + wid] = lsum;
    __syncthreads();
    float gsum = 0.f;
#pragma unroll
    for (int i = 0; i < 16; ++i) gsum += sred[16 + i];
    const float inv = 1.f / gsum;

    // PV: wave wid owns keys [256*wid, 256*wid+256), lane = d (coalesced V)
    {
      const int k0d = wid << 8;
      float a0 = 0.f, a1 = 0.f, a2 = 0.f, a3 = 0.f;
      for (int kk = 0; kk < 256; kk += 4) {
        a0 = fmaf(ssc[k0d + kk + 0], Vb[(size_t)(k0d + kk + 0) * DH + lane], a0);
        a1 = fmaf(ssc[k0d + kk + 1], Vb[(size_t)(k0d + kk + 1) * DH + lane], a1);
        a2 = fmaf(ssc[k0d + kk + 2], Vb[(size_t)(k0d + kk + 2) * DH + lane], a2);
        a3 = fmaf(ssc[k0d + kk + 3], Vb[(size_t)(k0d + kk + 3) * DH + lane], a3);
      }
      spart[wid * 64 + lane] = (a0 + a1) + (a2 + a3);
    }
    __syncthreads();
    if (tid < 64) {
      float num = 0.f;
#pragma unroll
      for (int i = 0; i < 16; ++i) num += spart[i * 64 + tid];
      O[((size_t)b * S_LEN + dq) * DH + tid] = num * inv;
    }
  }
}

extern "C" void kernel_launch(void* const* d_in, const int* in_sizes, int n_in,
                              void* d_out, int out_size, void* d_ws, size_t ws_size,
                              hipStream_t stream) {
  const float* Q = (const float*)d_in[0];
  const float* K = (const float*)d_in[1];
  const float* V = (const float*)d_in[2];
  const int*   M = (const int*)d_in[3];
  float* O = (float*)d_out;
  attn_fwd<<<dim3(4 * (S_LEN / 64)), dim3(1024), 0, stream>>>(Q, K, V, M, O);
}